// Round 17
// baseline (1327.671 us; speedup 1.0000x reference)
//
#include <hip/hip_runtime.h>
#include <stdint.h>

typedef __attribute__((ext_vector_type(8))) short short8;
typedef __attribute__((ext_vector_type(4))) float f32x4;

#define DEV static __device__ __forceinline__

#define L2E 1.4426950408889634f

// ---------------- helpers ----------------
DEV unsigned short f2bf(float f){
  unsigned int u = __float_as_uint(f);
  u = (u + 0x7FFFu + ((u >> 16) & 1u)) >> 16;
  return (unsigned short)u;
}
DEV float bf2f(unsigned short u){
  return __uint_as_float(((unsigned int)u) << 16);
}
DEV float frcp(float x){ return __builtin_amdgcn_rcpf(x); }
// raw v_exp_f32 (2^x). Proven identical to exp2f on-chip (R5 == R6 bitwise).
DEV float exp2a(float x){ float r; asm("v_exp_f32 %0, %1" : "=v"(r) : "v"(x)); return r; }
// unpack bf16 half c (0=lo,1=hi) of a dword to float (runtime c OK: ternary select)
DEV float bfu(unsigned int u, int c){
  return c ? __uint_as_float(u & 0xFFFF0000u) : __uint_as_float(u << 16);
}
DEV float wredsum(float v){
  #pragma unroll
  for (int m = 32; m; m >>= 1) v += __shfl_xor(v, m);
  return v;
}
DEV float wredmax(float v){
  #pragma unroll
  for (int m = 32; m; m >>= 1) v = fmaxf(v, __shfl_xor(v, m));
  return v;
}

// dims
#define BB 64
#define NN 512
#define HH 512
#define HC 256

// ---------------- prep: weights -> bf16 (rows scaled by L2E / 2*L2E), combined bias ----------------
__global__ void prep_w(const float* __restrict__ wih, const float* __restrict__ whh,
                       const float* __restrict__ bih, const float* __restrict__ bhh,
                       unsigned short* __restrict__ wihb, unsigned short* __restrict__ whhb,
                       float* __restrict__ cbias)
{
  const int NW1 = 2*2*768*512;   // 1572864
  const int NW2 = 2*2*768*256;   // 786432
  const int NCB = 2*1536;        // 3072
  for (int i = blockIdx.x*256 + threadIdx.x; i < NW1+NW2+NCB; i += gridDim.x*256){
    if (i < NW1){
      const int row = (i >> 9) % 768;       // true mod-768
      const float sc = ((row >> 8) == 2) ? 2.f*L2E : L2E;
      wihb[i] = f2bf(wih[i] * sc);
    } else if (i < NW1+NW2){
      const int k = i - NW1;
      const int row = (k >> 8) % 768;       // true mod-768
      const float sc = ((row >> 8) == 2) ? 2.f*L2E : L2E;
      whhb[k] = f2bf(whh[k] * sc);          // bf16 (MFMA recurrence)
    } else {
      int k = i - NW1 - NW2;
      int L = k / 1536, r = k % 1536;
      int dd = r / 768, g = r % 768;
      int idx = (L*2 + dd)*768 + g;
      const float sc = (g >= 512) ? 2.f*L2E : L2E;
      // fold b_ih always; fold b_hh for r,z gates. b_hh[n] stays in recurrence.
      cbias[k] = (bih[idx] + (g < 512 ? bhh[idx] : 0.f)) * sc;
    }
  }
}

// ---------------- prep: mask x -> bf16 copy ----------------
__global__ void prep_x(const float* __restrict__ x, const int* __restrict__ nnode,
                       unsigned short* __restrict__ xpb)
{
  const int TOT4 = (BB*NN*HH) >> 2;  // 4194304
  for (int i = blockIdx.x*256 + threadIdx.x; i < TOT4; i += gridDim.x*256){
    const int e = i << 2;
    const int b = e >> 18;          // /(512*512)
    const int n = (e >> 9) & 511;
    float4 v = *(const float4*)(x + e);
    if (n >= nnode[b]) { v.x = 0.f; v.y = 0.f; v.z = 0.f; v.w = 0.f; }
    ushort4 o;
    o.x = f2bf(v.x); o.y = f2bf(v.y); o.z = f2bf(v.z); o.w = f2bf(v.w);
    *(ushort4*)(xpb + e) = o;
  }
}

// ---------------- input-gate GEMM: C[32768][1536] = A[32768][512] * W[1536][512]^T + cbias ----------------
// Output row layout is GATE-PERMUTED for gru_rec:
//   for n = dir*768 + g, g = cls*256 + j (cls=r/z/n, j = hidden idx in [0,256)):
//   newoff = dir*768 + (j>>5)*96 + (j&15)*6 + cls*2 + ((j>>4)&1)
__global__ __launch_bounds__(256, 2) void gemm_xg(
    const unsigned short* __restrict__ A,
    const unsigned short* __restrict__ W,
    const float* __restrict__ cbias,
    unsigned short* __restrict__ C)
{
  const int tid = threadIdx.x;
  const int l = tid & 63, wv = tid >> 6;
  const int col = l & 15, lq = l >> 4;
  const int n0 = blockIdx.x * 128;   // 12 n-tiles
  const int m0 = blockIdx.y * 128;   // 256 m-tiles
  const int wm = wv >> 1, wn = wv & 1;
  __shared__ char As[16384];   // [128 rows][64 k] bf16, 16B-slot XOR swizzle
  __shared__ char Ws[16384];

  f32x4 acc[4][4];
  #pragma unroll
  for (int a = 0; a < 4; a++)
    #pragma unroll
    for (int b2 = 0; b2 < 4; b2++) acc[a][b2] = (f32x4){0.f,0.f,0.f,0.f};

  short8 pa[4], pw[4];
  #pragma unroll
  for (int p = 0; p < 4; p++){
    const int qq = p*256 + tid, row = qq >> 3, sl = qq & 7;
    pa[p] = *(const short8*)(A + (m0+row)*512 + sl*8);
    pw[p] = *(const short8*)(W + (n0+row)*512 + sl*8);
  }

  for (int ko = 0; ko < 8; ++ko){
    __syncthreads();
    #pragma unroll
    for (int p = 0; p < 4; p++){
      const int qq = p*256 + tid, row = qq >> 3, sl = qq & 7;
      *(short8*)(As + row*128 + ((sl ^ (row & 7)) << 4)) = pa[p];
      *(short8*)(Ws + row*128 + ((sl ^ (row & 7)) << 4)) = pw[p];
    }
    __syncthreads();
    if (ko < 7){
      #pragma unroll
      for (int p = 0; p < 4; p++){
        const int qq = p*256 + tid, row = qq >> 3, sl = qq & 7;
        pa[p] = *(const short8*)(A + (m0+row)*512 + (ko+1)*64 + sl*8);
        pw[p] = *(const short8*)(W + (n0+row)*512 + (ko+1)*64 + sl*8);
      }
    }
    #pragma unroll
    for (int kt = 0; kt < 2; kt++){
      short8 af[4], bfr[4];
      #pragma unroll
      for (int mi = 0; mi < 4; mi++){
        const int r = wm*64 + mi*16 + col;
        af[mi] = *(const short8*)(As + r*128 + ((((kt<<2)|lq) ^ (r & 7)) << 4));
      }
      #pragma unroll
      for (int ni = 0; ni < 4; ni++){
        const int r = wn*64 + ni*16 + col;
        bfr[ni] = *(const short8*)(Ws + r*128 + ((((kt<<2)|lq) ^ (r & 7)) << 4));
      }
      #pragma unroll
      for (int mi = 0; mi < 4; mi++)
        #pragma unroll
        for (int ni = 0; ni < 4; ni++)
          acc[mi][ni] = __builtin_amdgcn_mfma_f32_16x16x32_bf16(af[mi], bfr[ni], acc[mi][ni], 0, 0, 0);
    }
  }
  // epilogue: C[m][perm(n)] = bf16(acc + cbias[n])
  #pragma unroll
  for (int ni = 0; ni < 4; ni++){
    const int n = n0 + wn*64 + ni*16 + col;
    const int dirn = (n >= 768) ? 1 : 0;
    const int g = n - dirn*768;
    const int cls = g >> 8;
    const int j = g & 255;
    const int noff = dirn*768 + (j >> 5)*96 + (j & 15)*6 + cls*2 + ((j >> 4) & 1);
    const float cb = cbias[n];
    #pragma unroll
    for (int mi = 0; mi < 4; mi++){
      const int m = m0 + wm*64 + mi*16 + lq*4;
      #pragma unroll
      for (int rg = 0; rg < 4; rg++)
        C[(m + rg)*1536 + noff] = f2bf(acc[mi][ni][rg] + cb);
    }
  }
}

// ---------------- GRU recurrence (v15: rotated-chunk schedule, early barrier) ----------------
// grid = 128 blocks (1 recurrence each): blockIdx.x = dir*64 + batch. 512 threads (8 waves).
// Wave w gate-tiles r:{2w,2w+1} z:{16+2w,+1} n:{32+2w,+1}; all 6 in regs. Broadcast-A.
// KEY: wave w's gate outputs ARE h-chunk w (j=32w..32w+31 = k-chunk kt=w). Per-wave DS
// ordering lets wave w read its OWN chunk without a barrier. Step schedule:
//   read own chunk -> 6 MFMAs -> lgkmcnt(0)+s_barrier+sched_barrier -> other 7 chunks
//   (42 MFMAs) -> gates -> ds_write own chunk.   (ONE barrier/step, placed where own-chunk
// MFMA issue (~116 cy) hides barrier skew + first-read latency (~120 cy).)
// Correctness: (i) own write->read same-wave in-order; (ii) cross-wave reads happen after
// barrier(t), every wave's write precedes its barrier(t) arrival (lgkmcnt(0) drains it);
// (iii) WAR: writes to HB_W(t) are post-barrier(t); all reads of it as HB_R(t-1) were
// pre-barrier(t). Rotation is baked into STORAGE order (bw[i][s] = chunk (w+s)&7, static s
// indexing — rule #20) with the runtime part only in precomputed LDS addresses rdo[s].
#define MFMA16(a,b,c) __builtin_amdgcn_mfma_f32_16x16x32_bf16(a, b, c, 0, 0, 0)

#define GRU_STEP(HB_R, HB_W, PF_CUR, PF_NXT, TCUR, TNEXT) do {                  \
  { const uint3 v3 = *(const uint3*)(xg + xgo + (TNEXT)*1536);                  \
    PF_NXT[0]=v3.x; PF_NXT[1]=v3.y; PF_NXT[2]=v3.z; }                           \
  f32x4 acc[6];                                                                 \
  _Pragma("unroll")                                                             \
  for (int i = 0; i < 6; i++) acc[i] = (f32x4){0.f,0.f,0.f,0.f};                \
  { const short8 a = *(const short8*)((HB_R) + rdo[0]);                         \
    _Pragma("unroll")                                                           \
    for (int i = 0; i < 6; i++) acc[i] = MFMA16(a, bw[i][0], acc[i]); }         \
  asm volatile("s_waitcnt lgkmcnt(0)" ::: "memory");                            \
  __builtin_amdgcn_s_barrier();                                                 \
  __builtin_amdgcn_sched_barrier(0);                                            \
  _Pragma("unroll")                                                             \
  for (int s = 1; s < 8; s++){                                                  \
    const short8 a = *(const short8*)((HB_R) + rdo[s]);                         \
    _Pragma("unroll")                                                           \
    for (int i = 0; i < 6; i++) acc[i] = MFMA16(a, bw[i][s], acc[i]);           \
  }                                                                             \
  if (lq < 2){                                                                  \
    const float ar = lq ? acc[1][0] : acc[0][0];                                \
    const float az = lq ? acc[3][0] : acc[2][0];                                \
    const float an = lq ? acc[5][0] : acc[4][0];                                \
    const float xr = bfu(PF_CUR[0], lq);                                        \
    const float xz = bfu(PF_CUR[1], lq);                                        \
    const float xn = bfu(PF_CUR[2], lq);                                        \
    const float r_ = frcp(1.f + exp2a(-(xr + ar)));                             \
    const float z_ = frcp(1.f + exp2a(-(xz + az)));                             \
    const float tt = xn + r_*(an + bh);                                         \
    const float n_ = 1.f - 2.f*frcp(1.f + exp2a(tt));                           \
    const float hn2 = n_ + z_*(hreg - n_);                                      \
    hreg = hn2;                                                                 \
    const unsigned short hb = f2bf(hn2);                                        \
    outb[obo + (TCUR)*512] = hb;                                                \
    *(unsigned short*)((HB_W) + jl*2) = hb;                                     \
  }                                                                             \
} while(0)

__global__ __launch_bounds__(512, 2) void gru_rec(
    const unsigned short* __restrict__ xg,  // [64][512][1536] bf16, gate-permuted rows (prescaled)
    const unsigned short* __restrict__ whhL,// [2][768][256] bf16 (this layer, row-scaled)
    const float* __restrict__ bhhL,         // [2][768] (this layer, raw)
    unsigned short* __restrict__ outb)      // [64][512][512] bf16, logical h layout
{
  const int tid = threadIdx.x;
  const int l = tid & 63, w = tid >> 6;       // 8 waves
  const int col = l & 15, lq = l >> 4;
  const int dir = blockIdx.x >> 6, bg = blockIdx.x & 63;

  __shared__ char hbuf0[512];      // h bf16 [256], double-buffered
  __shared__ char hbuf1[512];

  const unsigned short* whh_d = whhL + dir*768*256;

  // weight fragments in ROTATED storage: bw[i][s] = k-chunk (w+s)&7 of gate-tile i.
  // B-frag lane holds W[g = nt*16 + col][k = kt*32 + lq*8 .. +8]
  short8 bw[6][8];
  #pragma unroll
  for (int i = 0; i < 6; i++){
    const int nt = (i < 2) ? (2*w + i) : (i < 4) ? (16 + 2*w + (i-2)) : (32 + 2*w + (i-4));
    const int g = nt*16 + col;
    #pragma unroll
    for (int s = 0; s < 8; s++){
      const int kt = (w + s) & 7;
      bw[i][s] = *(const short8*)(whh_d + g*256 + kt*32 + lq*8);
    }
  }

  // rotated hbuf read offsets
  int rdo[8];
  #pragma unroll
  for (int s = 0; s < 8; s++)
    rdo[s] = ((w + s) & 7)*64 + lq*16;

  // this lane's output (valid for lq<2; lq>=2 aliases lq-2 but is exec-masked at store)
  const int jl = 32*w + (lq & 1)*16 + col;
  const float bh = bhhL[dir*768 + 512 + jl] * (2.f*L2E);

  if (tid < 128){
    ((unsigned int*)hbuf0)[tid] = 0u;
    ((unsigned int*)hbuf1)[tid] = 0u;
  }

  float hreg = 0.f;

  const int xgo = bg*(512*1536) + dir*768 + (w*16 + col)*6;
  const int obo = bg*(512*512) + dir*256 + jl;

  // prologue: prefetch step 0
  unsigned int pfA[3], pfB[3];
  const int t0 = dir ? 511 : 0;
  const int dstep = dir ? -1 : 1;
  { const uint3 v3 = *(const uint3*)(xg + xgo + t0*1536);
    pfA[0] = v3.x; pfA[1] = v3.y; pfA[2] = v3.z; }

  __syncthreads();

  int tc = t0;
  #pragma unroll 1
  for (int ss = 0; ss < 256; ss++){
    const int tA = tc;
    const int tB = tA + dstep;
    const int tC = (ss == 255) ? tB : (tB + dstep);
    GRU_STEP(hbuf0, hbuf1, pfA, pfB, tA, tB);
    GRU_STEP(hbuf1, hbuf0, pfB, pfA, tB, tC);
    tc = tC;
  }
}

// ---------------- residual + LayerNorm + raw attention score ----------------
// grid = B*N blocks of 64 threads (1 wave). blockIdx.x = b*512 + t.
__global__ void ln_score(
    const unsigned short* __restrict__ h2b, const float* __restrict__ x,
    const int* __restrict__ nnode,
    const float* __restrict__ gam, const float* __restrict__ bet,
    const float* __restrict__ watt,
    float* __restrict__ hln, float* __restrict__ scores)
{
  const int bidx = blockIdx.x;
  const int b = bidx >> 9, n = bidx & 511;
  const int l = threadIdx.x;
  const int base = bidx*512;
  const int i0 = l*8;
  const bool valid = n < nnode[b];

  const short8 hv = *(const short8*)(h2b + base + i0);
  float y[8];
  #pragma unroll
  for (int p = 0; p < 2; p++){
    float4 xv = (float4){0.f,0.f,0.f,0.f};
    if (valid) xv = *(const float4*)(x + base + i0 + p*4);
    y[p*4+0] = bf2f((unsigned short)hv[p*4+0]) + xv.x;
    y[p*4+1] = bf2f((unsigned short)hv[p*4+1]) + xv.y;
    y[p*4+2] = bf2f((unsigned short)hv[p*4+2]) + xv.z;
    y[p*4+3] = bf2f((unsigned short)hv[p*4+3]) + xv.w;
  }
  float s = 0.f, sq = 0.f;
  #pragma unroll
  for (int i = 0; i < 8; i++){ s += y[i]; sq += y[i]*y[i]; }
  s = wredsum(s); sq = wredsum(sq);
  const float mu = s * (1.f/512.f);
  const float rstd = rsqrtf(sq * (1.f/512.f) - mu*mu + 1e-5f);

  float dot = 0.f;
  #pragma unroll
  for (int p = 0; p < 2; p++){
    const float4 gv = *(const float4*)(gam + i0 + p*4);
    const float4 bv = *(const float4*)(bet + i0 + p*4);
    const float4 wv = *(const float4*)(watt + i0 + p*4);
    float4 o;
    o.x = (y[p*4+0] - mu)*rstd*gv.x + bv.x;
    o.y = (y[p*4+1] - mu)*rstd*gv.y + bv.y;
    o.z = (y[p*4+2] - mu)*rstd*gv.z + bv.z;
    o.w = (y[p*4+3] - mu)*rstd*gv.w + bv.w;
    dot += o.x*wv.x + o.y*wv.y + o.z*wv.z + o.w*wv.w;
    *(float4*)(hln + base + i0 + p*4) = o;
  }
  dot = wredsum(dot);
  if (l == 0) scores[bidx] = dot;
}

// ---------------- softmax + weighted pooling ----------------
// grid = 64 blocks (one per batch), 256 threads.
__global__ void attn_pool(
    const float* __restrict__ hln, const float* __restrict__ scores,
    const float* __restrict__ watt, const float* __restrict__ q,
    float* __restrict__ out)
{
  __shared__ float sc[512];
  __shared__ float red[12];
  const int tid = threadIdx.x, l = tid & 63, w = tid >> 6;
  const int b = blockIdx.x;

  float p = q[b*512 + tid]*watt[512 + tid] + q[b*512 + 256 + tid]*watt[768 + tid];
  p = wredsum(p);
  if (l == 0) red[w] = p;
  __syncthreads();
  const float qd = red[0] + red[1] + red[2] + red[3];

  float s0 = scores[b*512 + tid] + qd;        s0 = s0 > 0.f ? s0 : 0.01f*s0;
  float s1 = scores[b*512 + 256 + tid] + qd;  s1 = s1 > 0.f ? s1 : 0.01f*s1;
  float m_ = wredmax(fmaxf(s0, s1));
  if (l == 0) red[4 + w] = m_;
  __syncthreads();
  const float mx = fmaxf(fmaxf(red[4], red[5]), fmaxf(red[6], red[7]));
  const float e0 = __expf(s0 - mx), e1 = __expf(s1 - mx);
  sc[tid] = e0; sc[tid + 256] = e1;
  float ss = wredsum(e0 + e1);
  if (l == 0) red[8 + w] = ss;
  __syncthreads();
  const float rden = 1.f / (red[8] + red[9] + red[10] + red[11]);

  const int h0 = tid*2;
  float a0 = 0.f, a1 = 0.f;
  for (int t = 0; t < 512; t++){
    const float wv = sc[t];
    const float2 v = *(const float2*)(hln + (b*512 + t)*512 + h0);
    a0 += v.x*wv; a1 += v.y*wv;
  }
  out[b*512 + h0]     = a0 * rden;
  out[b*512 + h0 + 1] = a1 * rden;
}

// ---------------- launcher ----------------
extern "C" void kernel_launch(void* const* d_in, const int* in_sizes, int n_in,
                              void* d_out, int out_size, void* d_ws, size_t ws_size,
                              hipStream_t stream)
{
  (void)in_sizes; (void)n_in; (void)out_size; (void)ws_size;
  const float* x    = (const float*)d_in[0];
  const int*   nn   = (const int*)d_in[1];
  const float* wih  = (const float*)d_in[2];
  const float* whh  = (const float*)d_in[3];
  const float* bih  = (const float*)d_in[4];
  const float* bhh  = (const float*)d_in[5];
  const float* lg   = (const float*)d_in[6];
  const float* lb   = (const float*)d_in[7];
  const float* watt = (const float*)d_in[8];
  const float* q    = (const float*)d_in[9];
  float* out = (float*)d_out;

  // workspace layout (total ~197 MiB)
  char* ws = (char*)d_ws;
  unsigned short* xg_b = (unsigned short*)(ws + 0);           // 100663296 B  [64][512][1536] bf16 (gate-permuted)
  unsigned short* xp_b = (unsigned short*)(ws + 100663296);   // 33554432 B
  unsigned short* h1_b = (unsigned short*)(ws + 134217728);   // 33554432 B
  unsigned short* h2_b = (unsigned short*)(ws + 167772160);   // 33554432 B
  unsigned short* wihb = (unsigned short*)(ws + 201326592);   // 3145728 B
  unsigned short* whhb = (unsigned short*)(ws + 204472320);   // 1572864 B
  float*         cbias = (float*)(ws + 206045184);            // 12288 B
  float*        scores = (float*)(ws + 206057472);            // 131072 B
  float*           hln = (float*)(ws + 0);                    // 67108864 B, reuses xg region

  prep_w<<<dim3(1024), dim3(256), 0, stream>>>(wih, whh, bih, bhh, wihb, whhb, cbias);
  prep_x<<<dim3(2048), dim3(256), 0, stream>>>(x, nn, xp_b);

  // layer 0
  gemm_xg<<<dim3(12, 256), dim3(256), 0, stream>>>(xp_b, wihb, cbias, xg_b);
  gru_rec<<<dim3(128), dim3(512), 0, stream>>>(xg_b, whhb, bhh, h1_b);

  // layer 1
  gemm_xg<<<dim3(12, 256), dim3(256), 0, stream>>>(h1_b, wihb + 1536*512, cbias + 1536, xg_b);
  gru_rec<<<dim3(128), dim3(512), 0, stream>>>(xg_b, whhb + 2*768*256, bhh + 1536, h2_b);

  ln_score<<<dim3(64*512), dim3(64), 0, stream>>>(h2_b, x, nn, lg, lb, watt, hln, scores);
  attn_pool<<<dim3(64), dim3(256), 0, stream>>>(hln, scores, watt, q, out);
}

// Round 18
// 1312.364 us; speedup vs baseline: 1.0117x; 1.0117x over previous
//
#include <hip/hip_runtime.h>
#include <stdint.h>

typedef __attribute__((ext_vector_type(8))) short short8;
typedef __attribute__((ext_vector_type(4))) float f32x4;

#define DEV static __device__ __forceinline__

#define L2E 1.4426950408889634f

// ---------------- helpers ----------------
DEV unsigned short f2bf(float f){
  unsigned int u = __float_as_uint(f);
  u = (u + 0x7FFFu + ((u >> 16) & 1u)) >> 16;
  return (unsigned short)u;
}
DEV float bf2f(unsigned short u){
  return __uint_as_float(((unsigned int)u) << 16);
}
DEV float frcp(float x){ return __builtin_amdgcn_rcpf(x); }
// raw v_exp_f32 (2^x). Proven identical to exp2f on-chip (R5 == R6 bitwise).
DEV float exp2a(float x){ float r; asm("v_exp_f32 %0, %1" : "=v"(r) : "v"(x)); return r; }
// unpack bf16 half c (0=lo,1=hi) of a dword to float (runtime c OK: ternary select)
DEV float bfu(unsigned int u, int c){
  return c ? __uint_as_float(u & 0xFFFF0000u) : __uint_as_float(u << 16);
}
DEV float wredsum(float v){
  #pragma unroll
  for (int m = 32; m; m >>= 1) v += __shfl_xor(v, m);
  return v;
}
DEV float wredmax(float v){
  #pragma unroll
  for (int m = 32; m; m >>= 1) v = fmaxf(v, __shfl_xor(v, m));
  return v;
}

// dims
#define BB 64
#define NN 512
#define HH 512
#define HC 256

// ---------------- prep: weights -> bf16 (rows scaled by L2E / 2*L2E), combined bias ----------------
__global__ void prep_w(const float* __restrict__ wih, const float* __restrict__ whh,
                       const float* __restrict__ bih, const float* __restrict__ bhh,
                       unsigned short* __restrict__ wihb, unsigned short* __restrict__ whhb,
                       float* __restrict__ cbias)
{
  const int NW1 = 2*2*768*512;   // 1572864
  const int NW2 = 2*2*768*256;   // 786432
  const int NCB = 2*1536;        // 3072
  for (int i = blockIdx.x*256 + threadIdx.x; i < NW1+NW2+NCB; i += gridDim.x*256){
    if (i < NW1){
      const int row = (i >> 9) % 768;       // true mod-768
      const float sc = ((row >> 8) == 2) ? 2.f*L2E : L2E;
      wihb[i] = f2bf(wih[i] * sc);
    } else if (i < NW1+NW2){
      const int k = i - NW1;
      const int row = (k >> 8) % 768;       // true mod-768
      const float sc = ((row >> 8) == 2) ? 2.f*L2E : L2E;
      whhb[k] = f2bf(whh[k] * sc);          // bf16 (MFMA recurrence)
    } else {
      int k = i - NW1 - NW2;
      int L = k / 1536, r = k % 1536;
      int dd = r / 768, g = r % 768;
      int idx = (L*2 + dd)*768 + g;
      const float sc = (g >= 512) ? 2.f*L2E : L2E;
      // fold b_ih always; fold b_hh for r,z gates. b_hh[n] stays in recurrence.
      cbias[k] = (bih[idx] + (g < 512 ? bhh[idx] : 0.f)) * sc;
    }
  }
}

// ---------------- prep: mask x -> bf16 copy ----------------
__global__ void prep_x(const float* __restrict__ x, const int* __restrict__ nnode,
                       unsigned short* __restrict__ xpb)
{
  const int TOT4 = (BB*NN*HH) >> 2;  // 4194304
  for (int i = blockIdx.x*256 + threadIdx.x; i < TOT4; i += gridDim.x*256){
    const int e = i << 2;
    const int b = e >> 18;          // /(512*512)
    const int n = (e >> 9) & 511;
    float4 v = *(const float4*)(x + e);
    if (n >= nnode[b]) { v.x = 0.f; v.y = 0.f; v.z = 0.f; v.w = 0.f; }
    ushort4 o;
    o.x = f2bf(v.x); o.y = f2bf(v.y); o.z = f2bf(v.z); o.w = f2bf(v.w);
    *(ushort4*)(xpb + e) = o;
  }
}

// ---------------- input-gate GEMM: C[32768][1536] = A[32768][512] * W[1536][512]^T + cbias ----------------
// Output row layout is GATE-PERMUTED for gru_rec:
//   for n = dir*768 + g, g = cls*256 + j (cls=r/z/n, j = hidden idx in [0,256)):
//   newoff = dir*768 + (j>>5)*96 + (j&15)*6 + cls*2 + ((j>>4)&1)
__global__ __launch_bounds__(256, 2) void gemm_xg(
    const unsigned short* __restrict__ A,
    const unsigned short* __restrict__ W,
    const float* __restrict__ cbias,
    unsigned short* __restrict__ C)
{
  const int tid = threadIdx.x;
  const int l = tid & 63, wv = tid >> 6;
  const int col = l & 15, lq = l >> 4;
  const int n0 = blockIdx.x * 128;   // 12 n-tiles
  const int m0 = blockIdx.y * 128;   // 256 m-tiles
  const int wm = wv >> 1, wn = wv & 1;
  __shared__ char As[16384];   // [128 rows][64 k] bf16, 16B-slot XOR swizzle
  __shared__ char Ws[16384];

  f32x4 acc[4][4];
  #pragma unroll
  for (int a = 0; a < 4; a++)
    #pragma unroll
    for (int b2 = 0; b2 < 4; b2++) acc[a][b2] = (f32x4){0.f,0.f,0.f,0.f};

  short8 pa[4], pw[4];
  #pragma unroll
  for (int p = 0; p < 4; p++){
    const int qq = p*256 + tid, row = qq >> 3, sl = qq & 7;
    pa[p] = *(const short8*)(A + (m0+row)*512 + sl*8);
    pw[p] = *(const short8*)(W + (n0+row)*512 + sl*8);
  }

  for (int ko = 0; ko < 8; ++ko){
    __syncthreads();
    #pragma unroll
    for (int p = 0; p < 4; p++){
      const int qq = p*256 + tid, row = qq >> 3, sl = qq & 7;
      *(short8*)(As + row*128 + ((sl ^ (row & 7)) << 4)) = pa[p];
      *(short8*)(Ws + row*128 + ((sl ^ (row & 7)) << 4)) = pw[p];
    }
    __syncthreads();
    if (ko < 7){
      #pragma unroll
      for (int p = 0; p < 4; p++){
        const int qq = p*256 + tid, row = qq >> 3, sl = qq & 7;
        pa[p] = *(const short8*)(A + (m0+row)*512 + (ko+1)*64 + sl*8);
        pw[p] = *(const short8*)(W + (n0+row)*512 + (ko+1)*64 + sl*8);
      }
    }
    #pragma unroll
    for (int kt = 0; kt < 2; kt++){
      short8 af[4], bfr[4];
      #pragma unroll
      for (int mi = 0; mi < 4; mi++){
        const int r = wm*64 + mi*16 + col;
        af[mi] = *(const short8*)(As + r*128 + ((((kt<<2)|lq) ^ (r & 7)) << 4));
      }
      #pragma unroll
      for (int ni = 0; ni < 4; ni++){
        const int r = wn*64 + ni*16 + col;
        bfr[ni] = *(const short8*)(Ws + r*128 + ((((kt<<2)|lq) ^ (r & 7)) << 4));
      }
      #pragma unroll
      for (int mi = 0; mi < 4; mi++)
        #pragma unroll
        for (int ni = 0; ni < 4; ni++)
          acc[mi][ni] = __builtin_amdgcn_mfma_f32_16x16x32_bf16(af[mi], bfr[ni], acc[mi][ni], 0, 0, 0);
    }
  }
  // epilogue: C[m][perm(n)] = bf16(acc + cbias[n])
  #pragma unroll
  for (int ni = 0; ni < 4; ni++){
    const int n = n0 + wn*64 + ni*16 + col;
    const int dirn = (n >= 768) ? 1 : 0;
    const int g = n - dirn*768;
    const int cls = g >> 8;
    const int j = g & 255;
    const int noff = dirn*768 + (j >> 5)*96 + (j & 15)*6 + cls*2 + ((j >> 4) & 1);
    const float cb = cbias[n];
    #pragma unroll
    for (int mi = 0; mi < 4; mi++){
      const int m = m0 + wm*64 + mi*16 + lq*4;
      #pragma unroll
      for (int rg = 0; rg < 4; rg++)
        C[(m + rg)*1536 + noff] = f2bf(acc[mi][ni][rg] + cb);
    }
  }
}

// ---------------- GRU recurrence (v14 = R16: reg weights + relaxed barrier + lq-split gates) ----------------
// grid = 128 blocks (1 recurrence each): blockIdx.x = dir*64 + batch. 512 threads (8 waves).
// Wave w gate-tiles: r:{2w,2w+1} z:{16+2w,+1} n:{32+2w,+1}. All 6 tiles in regs (bw[6][8]).
// Broadcast-A: every C row equals the real batch row -> acc[i][0] identical across lanes'
// (lq,reg). lq==0 computes output c=0 (j=32w+col), lq==1 computes c=1 (j=32w+16+col).
// Relaxed barrier (no vmcnt drain of the fire-and-forget outb store): s_waitcnt lgkmcnt(0)
// + raw s_barrier + sched_barrier(0)  (rule #18 fence).
#define MFMA16(a,b,c) __builtin_amdgcn_mfma_f32_16x16x32_bf16(a, b, c, 0, 0, 0)

#define GRU_STEP(HB_R, HB_W, PF_CUR, PF_NXT, TCUR, TNEXT) do {                  \
  { const uint3 v3 = *(const uint3*)(xg + xgo + (TNEXT)*1536);                  \
    PF_NXT[0]=v3.x; PF_NXT[1]=v3.y; PF_NXT[2]=v3.z; }                           \
  f32x4 acc[6];                                                                 \
  _Pragma("unroll")                                                             \
  for (int i = 0; i < 6; i++) acc[i] = (f32x4){0.f,0.f,0.f,0.f};                \
  _Pragma("unroll")                                                             \
  for (int kt = 0; kt < 8; kt++){                                               \
    const short8 a = *(const short8*)((HB_R) + kt*64 + lq*16);                  \
    _Pragma("unroll")                                                           \
    for (int i = 0; i < 6; i++)                                                 \
      acc[i] = MFMA16(a, bw[i][kt], acc[i]);                                    \
  }                                                                             \
  if (lq < 2){                                                                  \
    const float ar = lq ? acc[1][0] : acc[0][0];                                \
    const float az = lq ? acc[3][0] : acc[2][0];                                \
    const float an = lq ? acc[5][0] : acc[4][0];                                \
    const float xr = bfu(PF_CUR[0], lq);                                        \
    const float xz = bfu(PF_CUR[1], lq);                                        \
    const float xn = bfu(PF_CUR[2], lq);                                        \
    const float r_ = frcp(1.f + exp2a(-(xr + ar)));                             \
    const float z_ = frcp(1.f + exp2a(-(xz + az)));                             \
    const float tt = xn + r_*(an + bh);                                         \
    const float n_ = 1.f - 2.f*frcp(1.f + exp2a(tt));                           \
    const float hn2 = n_ + z_*(hreg - n_);                                      \
    hreg = hn2;                                                                 \
    const unsigned short hb = f2bf(hn2);                                        \
    outb[obo + (TCUR)*512] = hb;                                                \
    *(unsigned short*)((HB_W) + jl*2) = hb;                                     \
  }                                                                             \
  asm volatile("s_waitcnt lgkmcnt(0)" ::: "memory");                            \
  __builtin_amdgcn_s_barrier();                                                 \
  __builtin_amdgcn_sched_barrier(0);                                            \
} while(0)

__global__ __launch_bounds__(512, 2) void gru_rec(
    const unsigned short* __restrict__ xg,  // [64][512][1536] bf16, gate-permuted rows (prescaled)
    const unsigned short* __restrict__ whhL,// [2][768][256] bf16 (this layer, row-scaled)
    const float* __restrict__ bhhL,         // [2][768] (this layer, raw)
    unsigned short* __restrict__ outb)      // [64][512][512] bf16, logical h layout
{
  const int tid = threadIdx.x;
  const int l = tid & 63, w = tid >> 6;       // 8 waves
  const int col = l & 15, lq = l >> 4;
  const int dir = blockIdx.x >> 6, bg = blockIdx.x & 63;

  __shared__ char hbuf0[512];      // h bf16 [256], double-buffered
  __shared__ char hbuf1[512];

  const unsigned short* whh_d = whhL + dir*768*256;

  // weight fragments: B-frag lane holds W[g = nt*16 + col][k = kt*32 + lq*8 .. +8]
  short8 bw[6][8];
  #pragma unroll
  for (int i = 0; i < 6; i++){
    const int nt = (i < 2) ? (2*w + i) : (i < 4) ? (16 + 2*w + (i-2)) : (32 + 2*w + (i-4));
    const int g = nt*16 + col;
    #pragma unroll
    for (int kt = 0; kt < 8; kt++)
      bw[i][kt] = *(const short8*)(whh_d + g*256 + kt*32 + lq*8);
  }

  // this lane's output (valid for lq<2; lq>=2 aliases lq-2 but is exec-masked at store)
  const int jl = 32*w + (lq & 1)*16 + col;
  const float bh = bhhL[dir*768 + 512 + jl] * (2.f*L2E);

  if (tid < 128){
    ((unsigned int*)hbuf0)[tid] = 0u;
    ((unsigned int*)hbuf1)[tid] = 0u;
  }

  float hreg = 0.f;

  const int xgo = bg*(512*1536) + dir*768 + (w*16 + col)*6;
  const int obo = bg*(512*512) + dir*256 + jl;

  // prologue: prefetch step 0
  unsigned int pfA[3], pfB[3];
  const int t0 = dir ? 511 : 0;
  const int dstep = dir ? -1 : 1;
  { const uint3 v3 = *(const uint3*)(xg + xgo + t0*1536);
    pfA[0] = v3.x; pfA[1] = v3.y; pfA[2] = v3.z; }

  __syncthreads();

  int tc = t0;
  #pragma unroll 1
  for (int ss = 0; ss < 256; ss++){
    const int tA = tc;
    const int tB = tA + dstep;
    const int tC = (ss == 255) ? tB : (tB + dstep);
    GRU_STEP(hbuf0, hbuf1, pfA, pfB, tA, tB);
    GRU_STEP(hbuf1, hbuf0, pfB, pfA, tB, tC);
    tc = tC;
  }
}

// ---------------- residual + LayerNorm + raw attention score ----------------
// grid = B*N blocks of 64 threads (1 wave). blockIdx.x = b*512 + t.
__global__ void ln_score(
    const unsigned short* __restrict__ h2b, const float* __restrict__ x,
    const int* __restrict__ nnode,
    const float* __restrict__ gam, const float* __restrict__ bet,
    const float* __restrict__ watt,
    float* __restrict__ hln, float* __restrict__ scores)
{
  const int bidx = blockIdx.x;
  const int b = bidx >> 9, n = bidx & 511;
  const int l = threadIdx.x;
  const int base = bidx*512;
  const int i0 = l*8;
  const bool valid = n < nnode[b];

  const short8 hv = *(const short8*)(h2b + base + i0);
  float y[8];
  #pragma unroll
  for (int p = 0; p < 2; p++){
    float4 xv = (float4){0.f,0.f,0.f,0.f};
    if (valid) xv = *(const float4*)(x + base + i0 + p*4);
    y[p*4+0] = bf2f((unsigned short)hv[p*4+0]) + xv.x;
    y[p*4+1] = bf2f((unsigned short)hv[p*4+1]) + xv.y;
    y[p*4+2] = bf2f((unsigned short)hv[p*4+2]) + xv.z;
    y[p*4+3] = bf2f((unsigned short)hv[p*4+3]) + xv.w;
  }
  float s = 0.f, sq = 0.f;
  #pragma unroll
  for (int i = 0; i < 8; i++){ s += y[i]; sq += y[i]*y[i]; }
  s = wredsum(s); sq = wredsum(sq);
  const float mu = s * (1.f/512.f);
  const float rstd = rsqrtf(sq * (1.f/512.f) - mu*mu + 1e-5f);

  float dot = 0.f;
  #pragma unroll
  for (int p = 0; p < 2; p++){
    const float4 gv = *(const float4*)(gam + i0 + p*4);
    const float4 bv = *(const float4*)(bet + i0 + p*4);
    const float4 wv = *(const float4*)(watt + i0 + p*4);
    float4 o;
    o.x = (y[p*4+0] - mu)*rstd*gv.x + bv.x;
    o.y = (y[p*4+1] - mu)*rstd*gv.y + bv.y;
    o.z = (y[p*4+2] - mu)*rstd*gv.z + bv.z;
    o.w = (y[p*4+3] - mu)*rstd*gv.w + bv.w;
    dot += o.x*wv.x + o.y*wv.y + o.z*wv.z + o.w*wv.w;
    *(float4*)(hln + base + i0 + p*4) = o;
  }
  dot = wredsum(dot);
  if (l == 0) scores[bidx] = dot;
}

// ---------------- attention pooling, stage 1: per-(batch, t-chunk) partial sums ----------------
// grid = (64, 8), 256 threads. Block (b, s) pools t in [64s, 64s+64) into part[s][b][512].
// Softmax stats (qd, max) are recomputed redundantly per block (cheap: 512 scores);
// block s==0 also writes denom[b]. Deterministic: fixed partial order, no atomics.
__global__ void attn_part(
    const float* __restrict__ hln, const float* __restrict__ scores,
    const float* __restrict__ watt, const float* __restrict__ q,
    float* __restrict__ part, float* __restrict__ denom)
{
  __shared__ float sc[64];
  __shared__ float red[12];
  const int tid = threadIdx.x, l = tid & 63, w = tid >> 6;
  const int b = blockIdx.x, s = blockIdx.y;

  float p = q[b*512 + tid]*watt[512 + tid] + q[b*512 + 256 + tid]*watt[768 + tid];
  p = wredsum(p);
  if (l == 0) red[w] = p;
  __syncthreads();
  const float qd = red[0] + red[1] + red[2] + red[3];

  float s0 = scores[b*512 + tid] + qd;        s0 = s0 > 0.f ? s0 : 0.01f*s0;
  float s1 = scores[b*512 + 256 + tid] + qd;  s1 = s1 > 0.f ? s1 : 0.01f*s1;
  float m_ = wredmax(fmaxf(s0, s1));
  if (l == 0) red[4 + w] = m_;
  __syncthreads();
  const float mx = fmaxf(fmaxf(red[4], red[5]), fmaxf(red[6], red[7]));
  const float e0 = __expf(s0 - mx), e1 = __expf(s1 - mx);

  // denom (block s==0 only writes)
  float ssum = wredsum(e0 + e1);
  if (l == 0) red[8 + w] = ssum;

  // this block's t-chunk exps: chunk s<4 holds t=tid (e0), s>=4 holds t=tid+256 (e1)
  if (s < 4){ if ((tid >> 6) == s)       sc[tid & 63] = e0; }
  else      { if ((tid >> 6) == s - 4)   sc[tid & 63] = e1; }
  __syncthreads();
  if (s == 0 && tid == 0) denom[b] = red[8] + red[9] + red[10] + red[11];

  const int h0 = tid*2;
  const int tb = b*512 + s*64;
  float a0 = 0.f, a1 = 0.f;
  for (int t = 0; t < 64; t++){
    const float wv = sc[t];
    const float2 v = *(const float2*)(hln + (tb + t)*512 + h0);
    a0 += v.x*wv; a1 += v.y*wv;
  }
  float2 o; o.x = a0; o.y = a1;
  *(float2*)(part + (s*64 + b)*512 + h0) = o;
}

// ---------------- attention pooling, stage 2: reduce 8 partials ----------------
// grid = 64 blocks, 256 threads.
__global__ void attn_red(
    const float* __restrict__ part, const float* __restrict__ denom,
    float* __restrict__ out)
{
  const int b = blockIdx.x, tid = threadIdx.x;
  const int h0 = tid*2;
  float a0 = 0.f, a1 = 0.f;
  #pragma unroll
  for (int s = 0; s < 8; s++){
    const float2 v = *(const float2*)(part + (s*64 + b)*512 + h0);
    a0 += v.x; a1 += v.y;
  }
  const float rd = 1.f / denom[b];
  out[b*512 + h0]     = a0 * rd;
  out[b*512 + h0 + 1] = a1 * rd;
}

// ---------------- launcher ----------------
extern "C" void kernel_launch(void* const* d_in, const int* in_sizes, int n_in,
                              void* d_out, int out_size, void* d_ws, size_t ws_size,
                              hipStream_t stream)
{
  (void)in_sizes; (void)n_in; (void)out_size; (void)ws_size;
  const float* x    = (const float*)d_in[0];
  const int*   nn   = (const int*)d_in[1];
  const float* wih  = (const float*)d_in[2];
  const float* whh  = (const float*)d_in[3];
  const float* bih  = (const float*)d_in[4];
  const float* bhh  = (const float*)d_in[5];
  const float* lg   = (const float*)d_in[6];
  const float* lb   = (const float*)d_in[7];
  const float* watt = (const float*)d_in[8];
  const float* q    = (const float*)d_in[9];
  float* out = (float*)d_out;

  // workspace layout (total ~197 MiB)
  char* ws = (char*)d_ws;
  unsigned short* xg_b = (unsigned short*)(ws + 0);           // 100663296 B  [64][512][1536] bf16 (gate-permuted)
  unsigned short* xp_b = (unsigned short*)(ws + 100663296);   // 33554432 B (dead after layer-0 gemm)
  unsigned short* h1_b = (unsigned short*)(ws + 134217728);   // 33554432 B
  unsigned short* h2_b = (unsigned short*)(ws + 167772160);   // 33554432 B
  unsigned short* wihb = (unsigned short*)(ws + 201326592);   // 3145728 B
  unsigned short* whhb = (unsigned short*)(ws + 204472320);   // 1572864 B
  float*         cbias = (float*)(ws + 206045184);            // 12288 B
  float*        scores = (float*)(ws + 206057472);            // 131072 B
  float*           hln = (float*)(ws + 0);                    // 67108864 B, reuses xg region
  float*          part = (float*)(ws + 100663296);            // 1048576 B, reuses xp_b region
  float*         denom = (float*)(ws + 101711872);            // 256 B

  prep_w<<<dim3(1024), dim3(256), 0, stream>>>(wih, whh, bih, bhh, wihb, whhb, cbias);
  prep_x<<<dim3(2048), dim3(256), 0, stream>>>(x, nn, xp_b);

  // layer 0
  gemm_xg<<<dim3(12, 256), dim3(256), 0, stream>>>(xp_b, wihb, cbias, xg_b);
  gru_rec<<<dim3(128), dim3(512), 0, stream>>>(xg_b, whhb, bhh, h1_b);

  // layer 1
  gemm_xg<<<dim3(12, 256), dim3(256), 0, stream>>>(h1_b, wihb + 1536*512, cbias + 1536, xg_b);
  gru_rec<<<dim3(128), dim3(512), 0, stream>>>(xg_b, whhb + 2*768*256, bhh + 1536, h2_b);

  ln_score<<<dim3(64*512), dim3(64), 0, stream>>>(h2_b, x, nn, lg, lb, watt, hln, scores);
  attn_part<<<dim3(64, 8), dim3(256), 0, stream>>>(hln, scores, watt, q, part, denom);
  attn_red<<<dim3(64), dim3(256), 0, stream>>>(part, denom, out);
}